// Round 1
// baseline (209.886 us; speedup 1.0000x reference)
//
#include <hip/hip_runtime.h>

// Problem constants: B=256, T=256, DM=384, DK=DV=64.
// out = softmax(causal(Q K^T / 8)) V,  Q=xWq, K=xWk, V=xWv.
//
// Strategy: bf16 MFMA (16x16x32) everywhere; fp32 accumulation.
//  k0: W[384,64]x3 fp32 -> Wt bf16 [3][64][384]  (B-frag-friendly transpose)
//  k1: fused QKV projection, M=65536 K=384 N=192 -> Q,K,V bf16 [65536][64] in ws
//  k2: per-(batch, 64-row q-tile) attention; K,Vt in LDS; full-row softmax in regs;
//      P round-trips through LDS (C-layout -> A-layout) reusing K's LDS region.

typedef __attribute__((ext_vector_type(8))) short short8;
typedef __attribute__((ext_vector_type(4))) float floatx4;

__device__ inline unsigned short f2bf(float f) {
  union { float f; unsigned u; } v; v.f = f;
  unsigned r = v.u + 0x7FFFu + ((v.u >> 16) & 1u);  // RNE
  return (unsigned short)(r >> 16);
}

// ---------------- kernel 0: weight transpose/convert ----------------
__global__ void wt_kernel(const float* __restrict__ wq, const float* __restrict__ wk,
                          const float* __restrict__ wv, unsigned short* __restrict__ wt) {
  int idx = blockIdx.x * 256 + threadIdx.x;      // [0, 3*384*64)
  if (idx >= 3 * 384 * 64) return;
  int mat = idx / (384 * 64);
  int rem = idx % (384 * 64);
  int k = rem >> 6, n = rem & 63;
  const float* w = (mat == 0) ? wq : ((mat == 1) ? wk : wv);
  wt[((size_t)mat * 64 + n) * 384 + k] = f2bf(w[rem]);
}

// ---------------- kernel 1: fused QKV projection ----------------
// block = 256 thr (4 waves); wave = 32 tokens x 192 cols; 512 blocks.
__global__ __launch_bounds__(256) void qkv_kernel(
    const float* __restrict__ x, const unsigned short* __restrict__ wt,
    unsigned short* __restrict__ q, unsigned short* __restrict__ k2,
    unsigned short* __restrict__ v) {
  int lane = threadIdx.x & 63;
  int wave = threadIdx.x >> 6;
  int m = lane & 15, quad = lane >> 4;
  int tokBase = blockIdx.x * 128 + wave * 32;

  floatx4 z = {0.f, 0.f, 0.f, 0.f};
  floatx4 acc[2][12];
#pragma unroll
  for (int a = 0; a < 2; ++a)
#pragma unroll
    for (int b = 0; b < 12; ++b) acc[a][b] = z;

#pragma unroll
  for (int ks = 0; ks < 12; ++ks) {
    short8 af[2];
#pragma unroll
    for (int mt = 0; mt < 2; ++mt) {
      const float* ap = x + (size_t)(tokBase + mt * 16 + m) * 384 + ks * 32 + quad * 8;
      float4 x0 = *(const float4*)ap;
      float4 x1 = *(const float4*)(ap + 4);
      short8 t;
      t[0] = (short)f2bf(x0.x); t[1] = (short)f2bf(x0.y);
      t[2] = (short)f2bf(x0.z); t[3] = (short)f2bf(x0.w);
      t[4] = (short)f2bf(x1.x); t[5] = (short)f2bf(x1.y);
      t[6] = (short)f2bf(x1.z); t[7] = (short)f2bf(x1.w);
      af[mt] = t;
    }
#pragma unroll
    for (int nt = 0; nt < 12; ++nt) {
      const short8 bf = *(const short8*)&wt[((size_t)(nt >> 2) * 64 + (nt & 3) * 16 + m) * 384 + ks * 32 + quad * 8];
      acc[0][nt] = __builtin_amdgcn_mfma_f32_16x16x32_bf16(af[0], bf, acc[0][nt], 0, 0, 0);
      acc[1][nt] = __builtin_amdgcn_mfma_f32_16x16x32_bf16(af[1], bf, acc[1][nt], 0, 0, 0);
    }
  }

#pragma unroll
  for (int mt = 0; mt < 2; ++mt)
#pragma unroll
    for (int nt = 0; nt < 12; ++nt) {
      unsigned short* op = (nt < 4) ? q : ((nt < 8) ? k2 : v);
      int ncol = (nt & 3) * 16;
#pragma unroll
      for (int j = 0; j < 4; ++j) {
        int row = tokBase + mt * 16 + quad * 4 + j;   // C-layout: row = quad*4+reg
        op[(size_t)row * 64 + ncol + m] = f2bf(acc[mt][nt][j]);
      }
    }
}

// ---------------- kernel 2: attention ----------------
// grid = B*4 blocks; block = 256 thr (4 waves); wave = 16 q-rows.
__global__ __launch_bounds__(256) void attn_kernel(
    const unsigned short* __restrict__ Q, const unsigned short* __restrict__ K,
    const unsigned short* __restrict__ V, float* __restrict__ out) {
  // sK [256][72] bf16 (pad 64->72: 2-way bank alias only, free). Reused for P.
  // sV transposed [64][264] bf16.
  __shared__ __align__(16) unsigned short sK[256 * 72];   // 36864 B
  __shared__ __align__(16) unsigned short sV[64 * 264];   // 33792 B

  int tid = threadIdx.x;
  int lane = tid & 63, wave = tid >> 6;
  int m = lane & 15, quad = lane >> 4;
  int b = blockIdx.x >> 2, qt = blockIdx.x & 3;

  // stage K: vectorized 16B copies
  const unsigned short* Kg = K + (size_t)b * 256 * 64;
#pragma unroll
  for (int it = 0; it < 8; ++it) {
    int s = it * 32 + (tid >> 3);
    int c = (tid & 7) * 8;
    *(uint4*)&sK[s * 72 + c] = *(const uint4*)&Kg[s * 64 + c];
  }
  // stage V transposed (scalar; one-time cost per block)
  const unsigned short* Vg = V + (size_t)b * 256 * 64;
#pragma unroll 4
  for (int it = 0; it < 64; ++it) {
    int idx = it * 256 + tid;
    sV[(idx & 63) * 264 + (idx >> 6)] = Vg[idx];
  }

  // Q fragments (A-operand: m=lane&15 row, k=quad*8+j), K=64 -> 2 k-steps
  int qrow = qt * 64 + wave * 16 + m;
  const unsigned short* Qg = Q + ((size_t)b * 256 + qrow) * 64;
  short8 qf0 = *(const short8*)&Qg[quad * 8];
  short8 qf1 = *(const short8*)&Qg[32 + quad * 8];

  __syncthreads();

  // S = Q K^T : 16 col-tiles of 16, acc 64 f32/lane
  floatx4 z = {0.f, 0.f, 0.f, 0.f};
  floatx4 sacc[16];
#pragma unroll
  for (int nt = 0; nt < 16; ++nt) sacc[nt] = z;
#pragma unroll
  for (int nt = 0; nt < 16; ++nt) {
    short8 kb0 = *(const short8*)&sK[(nt * 16 + m) * 72 + quad * 8];
    short8 kb1 = *(const short8*)&sK[(nt * 16 + m) * 72 + 32 + quad * 8];
    sacc[nt] = __builtin_amdgcn_mfma_f32_16x16x32_bf16(qf0, kb0, sacc[nt], 0, 0, 0);
    sacc[nt] = __builtin_amdgcn_mfma_f32_16x16x32_bf16(qf1, kb1, sacc[nt], 0, 0, 0);
  }

  // causal mask + row softmax. C-layout: col = nt*16 + m, row = quad*4 + j.
  // Row r lives in the 16 lanes sharing `quad` -> shuffle-XOR over bits 0..3.
  const float CSC = 0.18033688011112042f;  // log2(e) * (1/sqrt(64))
  const float NEG = -3.0e38f;
  float inv[4];
  int rbase = qt * 64 + wave * 16 + quad * 4;
#pragma unroll
  for (int j = 0; j < 4; ++j) {
    int rg = rbase + j;
    float mx = NEG;
#pragma unroll
    for (int nt = 0; nt < 16; ++nt) {
      int col = nt * 16 + m;
      float sv = sacc[nt][j];
      if (col > rg) { sv = NEG; sacc[nt][j] = sv; }
      mx = fmaxf(mx, sv);
    }
    mx = fmaxf(mx, __shfl_xor(mx, 1));
    mx = fmaxf(mx, __shfl_xor(mx, 2));
    mx = fmaxf(mx, __shfl_xor(mx, 4));
    mx = fmaxf(mx, __shfl_xor(mx, 8));
    float sum = 0.f;
#pragma unroll
    for (int nt = 0; nt < 16; ++nt) {
      float p = exp2f((sacc[nt][j] - mx) * CSC);
      sacc[nt][j] = p;
      sum += p;
    }
    sum += __shfl_xor(sum, 1);
    sum += __shfl_xor(sum, 2);
    sum += __shfl_xor(sum, 4);
    sum += __shfl_xor(sum, 8);
    inv[j] = 1.f / sum;   // diagonal term guarantees sum >= 1
  }

  __syncthreads();   // all waves done reading sK -> safe to overwrite with P

  // P: C-layout -> LDS row-major [16][264] per wave (A-layout-readable)
  unsigned short* sP = sK + wave * (16 * 264);
#pragma unroll
  for (int nt = 0; nt < 16; ++nt)
#pragma unroll
    for (int j = 0; j < 4; ++j)
      sP[(quad * 4 + j) * 264 + nt * 16 + m] = f2bf(sacc[nt][j] * inv[j]);

  __syncthreads();

  // O = P V : M=16, N=64, K=256 (8 k-steps x 4 n-tiles)
  floatx4 o[4];
#pragma unroll
  for (int vt = 0; vt < 4; ++vt) o[vt] = z;
#pragma unroll
  for (int ks = 0; ks < 8; ++ks) {
    short8 pf = *(const short8*)&sP[m * 264 + ks * 32 + quad * 8];
#pragma unroll
    for (int vt = 0; vt < 4; ++vt) {
      short8 vb = *(const short8*)&sV[(vt * 16 + m) * 264 + ks * 32 + quad * 8];
      o[vt] = __builtin_amdgcn_mfma_f32_16x16x32_bf16(pf, vb, o[vt], 0, 0, 0);
    }
  }

  float* op = out + ((size_t)b * 256 + qt * 64 + wave * 16) * 64;
#pragma unroll
  for (int vt = 0; vt < 4; ++vt)
#pragma unroll
    for (int j = 0; j < 4; ++j)
      op[(quad * 4 + j) * 64 + vt * 16 + m] = o[vt][j];
}

extern "C" void kernel_launch(void* const* d_in, const int* in_sizes, int n_in,
                              void* d_out, int out_size, void* d_ws, size_t ws_size,
                              hipStream_t stream) {
  const float* x  = (const float*)d_in[0];
  const float* wq = (const float*)d_in[1];
  const float* wk = (const float*)d_in[2];
  const float* wv = (const float*)d_in[3];
  float* out = (float*)d_out;

  // ws layout: Wt bf16 [3][64][384] = 147456 B, then Q,K,V bf16 [65536][64] = 8 MiB each
  unsigned short* wt = (unsigned short*)d_ws;
  unsigned short* q  = (unsigned short*)((char*)d_ws + 147456);
  unsigned short* k  = q + (size_t)65536 * 64;
  unsigned short* v  = k + (size_t)65536 * 64;

  wt_kernel<<<288, 256, 0, stream>>>(wq, wk, wv, wt);
  qkv_kernel<<<512, 256, 0, stream>>>(x, wt, q, k, v);
  attn_kernel<<<256 * 4, 256, 0, stream>>>(q, k, v, out);
}

// Round 2
// 194.482 us; speedup vs baseline: 1.0792x; 1.0792x over previous
//
#include <hip/hip_runtime.h>

// B=256, T=256, DM=384, DK=DV=64.
// k0: W -> Wt bf16 [192 cols][384 k]   (coalesced-output transpose)
// k1: qkv GEMM M=65536 N=192 K=384, glds double-buffered, XOR-swizzled LDS;
//     writes Q,K row-major bf16 and V TRANSPOSED [b][64 col][256 tok] bf16.
// k2: attention per (batch, 64-row q-tile); K + pre-transposed V staged to LDS
//     with vectorized copies; full-row softmax in regs; P via LDS (C->A layout).

typedef __attribute__((ext_vector_type(8))) short short8;
typedef __attribute__((ext_vector_type(4))) float floatx4;

__device__ inline unsigned short f2bf(float f) {
  union { float f; unsigned u; } v; v.f = f;
  unsigned r = v.u + 0x7FFFu + ((v.u >> 16) & 1u);  // RNE
  return (unsigned short)(r >> 16);
}

__device__ inline void glds16(const void* g, void* l) {
  __builtin_amdgcn_global_load_lds(
      (const __attribute__((address_space(1))) void*)g,
      (__attribute__((address_space(3))) void*)l, 16, 0, 0);
}

// ---------------- kernel 0: weight transpose/convert (output-indexed) -------
__global__ void wt_kernel(const float* __restrict__ wq, const float* __restrict__ wk,
                          const float* __restrict__ wv, unsigned short* __restrict__ wt) {
  int idx = blockIdx.x * 256 + threadIdx.x;      // enumerates OUTPUT [mat][n][k]
  if (idx >= 3 * 64 * 384) return;
  int mat = idx / (64 * 384);
  int rem = idx % (64 * 384);
  int n = rem / 384, k = rem % 384;
  const float* w = (mat == 0) ? wq : ((mat == 1) ? wk : wv);
  wt[idx] = f2bf(w[k * 64 + n]);                 // coalesced write, L2-absorbed read
}

// ---------------- kernel 1: fused QKV projection ----------------
// grid = 1024 blocks; block = 256 thr (4 waves) = 64 tokens x 192 cols.
// Wave w: all 64 tokens x cols [48w, 48w+48).  12 k-chunks of 32.
__global__ __launch_bounds__(256, 4) void qkv_kernel(
    const float* __restrict__ x, const unsigned short* __restrict__ wt,
    unsigned short* __restrict__ q, unsigned short* __restrict__ kk,
    unsigned short* __restrict__ vt) {
  // xa: fp32 x-tile [64 rows][32 k], XOR-swizzled in 16B granules. 8KB x2.
  // wb: bf16 Wt-tile [192 cols][32 k], XOR-swizzled. 12KB x2.
  __shared__ __align__(16) float          xa[2][64 * 32];
  __shared__ __align__(16) unsigned short wb[2][192 * 32];

  int tid = threadIdx.x, lane = tid & 63, w = tid >> 6;
  int m = lane & 15, quad = lane >> 4;
  int tok0 = blockIdx.x * 64;

  floatx4 z = {0.f, 0.f, 0.f, 0.f};
  floatx4 acc[4][3];
#pragma unroll
  for (int a = 0; a < 4; ++a)
#pragma unroll
    for (int b = 0; b < 3; ++b) acc[a][b] = z;

  // async staging of chunk ks into buffer buf (all global reads coalesced 1KB/wave)
  auto stage = [&](int ks, int buf) {
    // xa: 2 issues/wave; issue a covers rows [8a, 8a+8)
#pragma unroll
    for (int i = 0; i < 2; ++i) {
      int a = w * 2 + i;
      int row = a * 8 + (lane >> 3);
      int kq = (lane & 7) ^ (row & 7);          // swizzle: LDS slot (lane&7) <- global group kq
      glds16(x + (size_t)(tok0 + row) * 384 + ks * 32 + kq * 4,
             (void*)&xa[buf][a * 256]);
    }
    // wb: 3 issues/wave; issue g covers cols [16g, 16g+16)
#pragma unroll
    for (int i = 0; i < 3; ++i) {
      int g = w * 3 + i;
      int c = g * 16 + (lane >> 2);
      int kq = (lane & 3) ^ (c & 3) ^ ((c >> 2) & 3);
      glds16(wt + (size_t)c * 384 + ks * 32 + kq * 8,
             (void*)&wb[buf][g * 512]);
    }
  };

  stage(0, 0);
#pragma unroll 1
  for (int ks = 0; ks < 12; ++ks) {
    int buf = ks & 1;
    __syncthreads();                    // chunk ks staged; prior reads of buf done
    if (ks < 11) stage(ks + 1, buf ^ 1);

    // A fragments: fp32 from swizzled LDS -> convert -> short8
    short8 af[4];
#pragma unroll
    for (int mt = 0; mt < 4; ++mt) {
      int r = mt * 16 + m;
      int s0 = (2 * quad) ^ (m & 7);
      int s1 = (2 * quad + 1) ^ (m & 7);
      float4 f0 = *(const float4*)&xa[buf][r * 32 + s0 * 4];
      float4 f1 = *(const float4*)&xa[buf][r * 32 + s1 * 4];
      short8 t;
      t[0] = (short)f2bf(f0.x); t[1] = (short)f2bf(f0.y);
      t[2] = (short)f2bf(f0.z); t[3] = (short)f2bf(f0.w);
      t[4] = (short)f2bf(f1.x); t[5] = (short)f2bf(f1.y);
      t[6] = (short)f2bf(f1.z); t[7] = (short)f2bf(f1.w);
      af[mt] = t;
    }
    // B fragments: bf16 from swizzled LDS
    short8 bf[3];
#pragma unroll
    for (int nt = 0; nt < 3; ++nt) {
      int c = w * 48 + nt * 16 + m;
      int sq = quad ^ (c & 3) ^ ((c >> 2) & 3);
      bf[nt] = *(const short8*)&wb[buf][c * 32 + sq * 8];
    }
#pragma unroll
    for (int mt = 0; mt < 4; ++mt)
#pragma unroll
      for (int nt = 0; nt < 3; ++nt)
        acc[mt][nt] = __builtin_amdgcn_mfma_f32_16x16x32_bf16(af[mt], bf[nt], acc[mt][nt], 0, 0, 0);
  }

  __syncthreads();                       // done with xa -> reuse as vtile
  unsigned short* vtile = (unsigned short*)&xa[0][0];   // [64 vcol][64 tok] pad 72

#pragma unroll
  for (int mt = 0; mt < 4; ++mt)
#pragma unroll
    for (int nt = 0; nt < 3; ++nt) {
      int cb = w * 48 + nt * 16;
#pragma unroll
      for (int j = 0; j < 4; ++j) {
        int row = mt * 16 + quad * 4 + j;           // local token (C-layout row)
        unsigned short val = f2bf(acc[mt][nt][j]);
        if (cb < 64)        q [(size_t)(tok0 + row) * 64 + cb + m]       = val;
        else if (cb < 128)  kk[(size_t)(tok0 + row) * 64 + cb - 64 + m]  = val;
        else                vtile[(cb - 128 + m) * 72 + row] = val;
      }
    }

  __syncthreads();
  // cooperative coalesced V^T store: vt[b][col][tok]
  {
    int c = tid >> 2, t4 = tid & 3;
    int bb = tok0 >> 8, tm = tok0 & 255;
    uint4 d0 = *(const uint4*)&vtile[c * 72 + t4 * 16];
    uint4 d1 = *(const uint4*)&vtile[c * 72 + t4 * 16 + 8];
    size_t base = ((size_t)bb * 64 + c) * 256 + tm + t4 * 16;
    *(uint4*)&vt[base]     = d0;
    *(uint4*)&vt[base + 8] = d1;
  }
}

// ---------------- kernel 2: attention ----------------
// grid = B*4; block = 256 thr (4 waves); wave = 16 q-rows.
__global__ __launch_bounds__(256) void attn_kernel(
    const unsigned short* __restrict__ Q, const unsigned short* __restrict__ K,
    const unsigned short* __restrict__ Vt, float* __restrict__ out) {
  __shared__ __align__(16) unsigned short sK[256 * 72];   // K [256][64 pad 72]; reused for P
  __shared__ __align__(16) unsigned short sV[64 * 264];   // V^T [64][256 pad 264]

  int tid = threadIdx.x;
  int lane = tid & 63, wave = tid >> 6;
  int m = lane & 15, quad = lane >> 4;
  int b = blockIdx.x >> 2, qt = blockIdx.x & 3;

  // stage K: vectorized 16B, coalesced
  const unsigned short* Kg = K + (size_t)b * 256 * 64;
#pragma unroll
  for (int it = 0; it < 8; ++it) {
    int s = it * 32 + (tid >> 3);
    int c = (tid & 7) * 8;
    *(uint4*)&sK[s * 72 + c] = *(const uint4*)&Kg[s * 64 + c];
  }
  // stage V^T: vectorized 16B, coalesced (pre-transposed in HBM)
  const unsigned short* Vg = Vt + (size_t)b * 64 * 256;
#pragma unroll
  for (int it = 0; it < 8; ++it) {
    int lin = it * 2048 + tid * 8;
    *(uint4*)&sV[(lin >> 8) * 264 + (lin & 255)] = *(const uint4*)&Vg[lin];
  }

  // Q fragments (A-operand), K=64 -> 2 k-steps
  int qrow = qt * 64 + wave * 16 + m;
  const unsigned short* Qg = Q + ((size_t)b * 256 + qrow) * 64;
  short8 qf0 = *(const short8*)&Qg[quad * 8];
  short8 qf1 = *(const short8*)&Qg[32 + quad * 8];

  __syncthreads();

  // S = Q K^T
  floatx4 z = {0.f, 0.f, 0.f, 0.f};
  floatx4 sacc[16];
#pragma unroll
  for (int nt = 0; nt < 16; ++nt) sacc[nt] = z;
#pragma unroll
  for (int nt = 0; nt < 16; ++nt) {
    short8 kb0 = *(const short8*)&sK[(nt * 16 + m) * 72 + quad * 8];
    short8 kb1 = *(const short8*)&sK[(nt * 16 + m) * 72 + 32 + quad * 8];
    sacc[nt] = __builtin_amdgcn_mfma_f32_16x16x32_bf16(qf0, kb0, sacc[nt], 0, 0, 0);
    sacc[nt] = __builtin_amdgcn_mfma_f32_16x16x32_bf16(qf1, kb1, sacc[nt], 0, 0, 0);
  }

  // causal mask + softmax; row r in the 16 lanes sharing quad -> shuffle over bits 0..3
  const float CSC = 0.18033688011112042f;  // log2(e)/sqrt(64)
  const float NEG = -3.0e38f;
  float inv[4];
  int rbase = qt * 64 + wave * 16 + quad * 4;
#pragma unroll
  for (int j = 0; j < 4; ++j) {
    int rg = rbase + j;
    float mx = NEG;
#pragma unroll
    for (int nt = 0; nt < 16; ++nt) {
      int col = nt * 16 + m;
      float sv = sacc[nt][j];
      if (col > rg) { sv = NEG; sacc[nt][j] = sv; }
      mx = fmaxf(mx, sv);
    }
    mx = fmaxf(mx, __shfl_xor(mx, 1));
    mx = fmaxf(mx, __shfl_xor(mx, 2));
    mx = fmaxf(mx, __shfl_xor(mx, 4));
    mx = fmaxf(mx, __shfl_xor(mx, 8));
    float sum = 0.f;
#pragma unroll
    for (int nt = 0; nt < 16; ++nt) {
      float p = exp2f((sacc[nt][j] - mx) * CSC);
      sacc[nt][j] = p;
      sum += p;
    }
    sum += __shfl_xor(sum, 1);
    sum += __shfl_xor(sum, 2);
    sum += __shfl_xor(sum, 4);
    sum += __shfl_xor(sum, 8);
    inv[j] = 1.f / sum;
  }

  __syncthreads();   // sK no longer needed -> reuse for P

  unsigned short* sP = sK + wave * (16 * 264);
#pragma unroll
  for (int nt = 0; nt < 16; ++nt)
#pragma unroll
    for (int j = 0; j < 4; ++j)
      sP[(quad * 4 + j) * 264 + nt * 16 + m] = f2bf(sacc[nt][j] * inv[j]);

  __syncthreads();

  // O = P V : 8 k-steps x 4 n-tiles
  floatx4 o[4];
#pragma unroll
  for (int vt = 0; vt < 4; ++vt) o[vt] = z;
#pragma unroll
  for (int ks = 0; ks < 8; ++ks) {
    short8 pf = *(const short8*)&sP[m * 264 + ks * 32 + quad * 8];
#pragma unroll
    for (int vt = 0; vt < 4; ++vt) {
      short8 vb = *(const short8*)&sV[(vt * 16 + m) * 264 + ks * 32 + quad * 8];
      o[vt] = __builtin_amdgcn_mfma_f32_16x16x32_bf16(pf, vb, o[vt], 0, 0, 0);
    }
  }

  float* op = out + ((size_t)b * 256 + qt * 64 + wave * 16) * 64;
#pragma unroll
  for (int vt = 0; vt < 4; ++vt)
#pragma unroll
    for (int j = 0; j < 4; ++j)
      op[(quad * 4 + j) * 64 + vt * 16 + m] = o[vt][j];
}

extern "C" void kernel_launch(void* const* d_in, const int* in_sizes, int n_in,
                              void* d_out, int out_size, void* d_ws, size_t ws_size,
                              hipStream_t stream) {
  const float* x  = (const float*)d_in[0];
  const float* wq = (const float*)d_in[1];
  const float* wk = (const float*)d_in[2];
  const float* wv = (const float*)d_in[3];
  float* out = (float*)d_out;

  // ws: Wt bf16 [192][384] = 147456 B; Q,K [65536][64] bf16; Vt [256][64][256] bf16
  unsigned short* wt = (unsigned short*)d_ws;
  unsigned short* q  = (unsigned short*)((char*)d_ws + 147456);
  unsigned short* k  = q + (size_t)65536 * 64;
  unsigned short* vt = k + (size_t)65536 * 64;

  wt_kernel<<<288, 256, 0, stream>>>(wq, wk, wv, wt);
  qkv_kernel<<<1024, 256, 0, stream>>>(x, wt, q, k, vt);
  attn_kernel<<<256 * 4, 256, 0, stream>>>(q, k, vt, out);
}

// Round 3
// 178.092 us; speedup vs baseline: 1.1785x; 1.0920x over previous
//
#include <hip/hip_runtime.h>

// B=256, T=256, DM=384, DK=DV=64.
// k0: W -> Wt bf16 [192 cols][384 k]  (coalesced-output transpose)
// k1: FUSED. One block per batch (1024 thr = 16 waves, 1 block/CU):
//     - stream x[b] in 12 k-chunks of 32 via global_load_lds (16B, XOR-swizzled)
//     - QKV MFMA: wave w owns token rows [16w,16w+16), all 192 cols (12 acc tiles)
//     - epilogue: K and V^T written straight to LDS (no HBM round-trip),
//       Q via per-wave scratch (dead staging region)
//     - attention fully in-LDS: S=QK^T (triangular skip), reg softmax,
//       P->per-wave scratch (C->A layout), PV from LDS V^T, fp32 out store.

typedef __attribute__((ext_vector_type(8))) short short8;
typedef __attribute__((ext_vector_type(4))) float floatx4;

__device__ inline unsigned short f2bf(float f) {
  union { float f; unsigned u; } v; v.f = f;
  unsigned r = v.u + 0x7FFFu + ((v.u >> 16) & 1u);  // RNE
  return (unsigned short)(r >> 16);
}

__device__ inline void glds16(const void* g, void* l) {
  __builtin_amdgcn_global_load_lds(
      (const __attribute__((address_space(1))) void*)g,
      (__attribute__((address_space(3))) void*)l, 16, 0, 0);
}

// ---------------- kernel 0: weight transpose/convert (output-indexed) -------
__global__ void wt_kernel(const float* __restrict__ wq, const float* __restrict__ wk,
                          const float* __restrict__ wv, unsigned short* __restrict__ wt) {
  int idx = blockIdx.x * 256 + threadIdx.x;      // enumerates OUTPUT [mat][n][k]
  if (idx >= 3 * 64 * 384) return;
  int mat = idx / (64 * 384);
  int rem = idx % (64 * 384);
  int n = rem / 384, k = rem % 384;
  const float* w = (mat == 0) ? wq : ((mat == 1) ? wk : wv);
  wt[idx] = f2bf(w[k * 64 + n]);
}

// ---------------- kernel 1: fused QKV + attention ----------------
__global__ __launch_bounds__(1024, 4) void fused_kernel(
    const float* __restrict__ x, const unsigned short* __restrict__ wt,
    float* __restrict__ out) {
  __shared__ __align__(16) unsigned short sK[256 * 72];    // 36864 B
  __shared__ __align__(16) unsigned short sVT[64 * 264];   // 33792 B
  __shared__ __align__(16) unsigned char stg[45056];       // xa 32KB + wb 12KB; later Q/P scratch
  float* xa = (float*)stg;                                  // [256 rows][32 k] f32, swizzled
  unsigned short* wb = (unsigned short*)(stg + 32768);      // [192 cols][32 k] bf16, swizzled

  int tid = threadIdx.x, lane = tid & 63, w = tid >> 6;
  int m = lane & 15, q = lane >> 4;
  int b = blockIdx.x;
  const float* xb = x + (size_t)b * 256 * 384;

  floatx4 z = {0.f, 0.f, 0.f, 0.f};
  floatx4 acc[12];
#pragma unroll
  for (int nt = 0; nt < 12; ++nt) acc[nt] = z;

  // ---------- QKV phase: 12 k-chunks of 32, single-buffered ----------
#pragma unroll 1
  for (int ks = 0; ks < 12; ++ks) {
    // stage x: 32 glds issues (8 rows each); wave w does issues 2w, 2w+1
#pragma unroll
    for (int i = 0; i < 2; ++i) {
      int a = 2 * w + i;
      int row = a * 8 + (lane >> 3);
      int g = (lane & 7) ^ (row & 7);          // slot lane&7 holds granule g
      glds16(xb + (size_t)row * 384 + ks * 32 + g * 4, (void*)(xa + a * 256));
    }
    // stage Wt: 12 issues (16 cols each); waves 0..11
    if (w < 12) {
      int c = w * 16 + (lane >> 2);
      int g = (lane & 3) ^ (c & 3);
      glds16(wt + (size_t)c * 384 + ks * 32 + g * 8, (void*)(wb + w * 512));
    }
    __syncthreads();                            // drains glds (vmcnt) + prior reads

    // A fragment: wave's 16 rows, k-chunk ks
    int r = w * 16 + m;                         // r&7 == m&7
    int s0 = (2 * q) ^ (m & 7);
    float4 f0 = *(const float4*)(xa + r * 32 + s0 * 4);
    float4 f1 = *(const float4*)(xa + r * 32 + (s0 ^ 1) * 4);
    short8 af;
    af[0] = (short)f2bf(f0.x); af[1] = (short)f2bf(f0.y);
    af[2] = (short)f2bf(f0.z); af[3] = (short)f2bf(f0.w);
    af[4] = (short)f2bf(f1.x); af[5] = (short)f2bf(f1.y);
    af[6] = (short)f2bf(f1.z); af[7] = (short)f2bf(f1.w);

#pragma unroll
    for (int nt = 0; nt < 12; ++nt) {
      int sq = q ^ (m & 3);                     // col c = nt*16+m, c&3 == m&3
      short8 bf = *(const short8*)(wb + (nt * 16 + m) * 32 + sq * 8);
      acc[nt] = __builtin_amdgcn_mfma_f32_16x16x32_bf16(af, bf, acc[nt], 0, 0, 0);
    }
    __syncthreads();                            // all reads done before next stage
  }

  // ---------- epilogue: Q -> per-wave scratch, K/V^T -> shared LDS ----------
  unsigned short* scr = (unsigned short*)stg + w * 1152;   // [16][72] bf16, 2304 B
#pragma unroll
  for (int nt = 0; nt < 12; ++nt) {
#pragma unroll
    for (int j = 0; j < 4; ++j) {
      unsigned short val = f2bf(acc[nt][j]);
      int lrow = q * 4 + j;                     // C-layout row within wave's 16
      int grow = w * 16 + lrow;                 // global token
      if (nt < 4)       scr[lrow * 72 + nt * 16 + m] = val;                 // Q
      else if (nt < 8)  sK[grow * 72 + (nt - 4) * 16 + m] = val;            // K
      else              sVT[((nt - 8) * 16 + m) * 264 + grow] = val;        // V^T
    }
  }

  // Q fragments from own scratch (wave-local; compiler orders write->read)
  short8 qf0 = *(const short8*)(scr + m * 72 + q * 8);
  short8 qf1 = *(const short8*)(scr + m * 72 + 32 + q * 8);

  __syncthreads();                              // sK, sVT visible to all waves

  // ---------- S = Q K^T (triangular: wave w needs col tiles nt <= w) ----------
  floatx4 sacc[16];
#pragma unroll
  for (int nt = 0; nt < 16; ++nt) {
    if (nt > w) continue;                       // wave-uniform skip
    short8 kb0 = *(const short8*)(sK + (nt * 16 + m) * 72 + q * 8);
    short8 kb1 = *(const short8*)(sK + (nt * 16 + m) * 72 + 32 + q * 8);
    floatx4 t = __builtin_amdgcn_mfma_f32_16x16x32_bf16(qf0, kb0, z, 0, 0, 0);
    sacc[nt] = __builtin_amdgcn_mfma_f32_16x16x32_bf16(qf1, kb1, t, 0, 0, 0);
  }

  // ---------- causal mask + softmax ----------
  const float CSC = 0.18033688011112042f;       // log2(e)/sqrt(64)
  const float NEG = -3.0e38f;
  float inv_[4];
  int rbase = w * 16 + q * 4;
#pragma unroll
  for (int j = 0; j < 4; ++j) {
    int rg = rbase + j;
    float mx = NEG;
#pragma unroll
    for (int nt = 0; nt < 16; ++nt) {
      if (nt > w) continue;
      int col = nt * 16 + m;
      float sv = sacc[nt][j];
      if (col > rg) { sv = NEG; sacc[nt][j] = sv; }
      mx = fmaxf(mx, sv);
    }
    mx = fmaxf(mx, __shfl_xor(mx, 1));
    mx = fmaxf(mx, __shfl_xor(mx, 2));
    mx = fmaxf(mx, __shfl_xor(mx, 4));
    mx = fmaxf(mx, __shfl_xor(mx, 8));
    float sum = 0.f;
#pragma unroll
    for (int nt = 0; nt < 16; ++nt) {
      if (nt > w) continue;
      float p = exp2f((sacc[nt][j] - mx) * CSC);
      sacc[nt][j] = p;
      sum += p;
    }
    sum += __shfl_xor(sum, 1);
    sum += __shfl_xor(sum, 2);
    sum += __shfl_xor(sum, 4);
    sum += __shfl_xor(sum, 8);
    inv_[j] = 1.f / sum;                        // diagonal term -> sum >= 1
  }

  // ---------- O = P V, chunked by 64 k-cols through per-wave scratch ----------
  floatx4 o[4];
#pragma unroll
  for (int vt = 0; vt < 4; ++vt) o[vt] = z;
#pragma unroll
  for (int c = 0; c < 4; ++c) {
    if (4 * c > w) continue;                    // chunk needed iff 64c <= 16w+15
    // write P chunk [16 rows][64 cols] (C-layout -> A-layout); zero beyond diag tile
#pragma unroll
    for (int t = 0; t < 4; ++t) {
      int nt = 4 * c + t;
#pragma unroll
      for (int j = 0; j < 4; ++j) {
        unsigned short pv = (nt <= w) ? f2bf(sacc[nt][j] * inv_[j]) : (unsigned short)0;
        scr[(q * 4 + j) * 72 + t * 16 + m] = pv;
      }
    }
    short8 pf0 = *(const short8*)(scr + m * 72 + q * 8);
    short8 pf1 = *(const short8*)(scr + m * 72 + 32 + q * 8);
#pragma unroll
    for (int vt = 0; vt < 4; ++vt) {
      short8 vb0 = *(const short8*)(sVT + (vt * 16 + m) * 264 + c * 64 + q * 8);
      short8 vb1 = *(const short8*)(sVT + (vt * 16 + m) * 264 + c * 64 + 32 + q * 8);
      o[vt] = __builtin_amdgcn_mfma_f32_16x16x32_bf16(pf0, vb0, o[vt], 0, 0, 0);
      o[vt] = __builtin_amdgcn_mfma_f32_16x16x32_bf16(pf1, vb1, o[vt], 0, 0, 0);
    }
  }

  // ---------- store O ----------
  float* op = out + ((size_t)b * 256 + w * 16) * 64;
#pragma unroll
  for (int vt = 0; vt < 4; ++vt)
#pragma unroll
    for (int j = 0; j < 4; ++j)
      op[(q * 4 + j) * 64 + vt * 16 + m] = o[vt][j];
}

extern "C" void kernel_launch(void* const* d_in, const int* in_sizes, int n_in,
                              void* d_out, int out_size, void* d_ws, size_t ws_size,
                              hipStream_t stream) {
  const float* x  = (const float*)d_in[0];
  const float* wq = (const float*)d_in[1];
  const float* wk = (const float*)d_in[2];
  const float* wv = (const float*)d_in[3];
  float* out = (float*)d_out;

  unsigned short* wt = (unsigned short*)d_ws;   // Wt bf16 [192][384] = 147456 B

  wt_kernel<<<288, 256, 0, stream>>>(wq, wk, wv, wt);
  fused_kernel<<<256, 1024, 0, stream>>>(x, wt, out);
}

// Round 4
// 170.781 us; speedup vs baseline: 1.2290x; 1.0428x over previous
//
#include <hip/hip_runtime.h>

// B=256, T=256, DM=384, DK=DV=64.
// k0: W -> Wt bf16 [192 cols][384 k]  (coalesced-output transpose)
// k1: FUSED, one block/batch (1024 thr = 16 waves):
//   Phase 1 (QKV GEMM): wave w owns token rows [16w,16w+16) x all 192 cols.
//     A (x fp32) -> straight to VGPRs (coalesced, read once, no LDS).
//     B (Wt bf16) -> LDS via global_load_lds in 4 double-buffered mega-chunks
//     of 3 k-chunks (36.9KB); only 4 barriers, barrier-free inside a mega.
//   Phase 2: Q -> per-wave scratch (dead wb region), K -> sK, V^T -> sVT
//     (packed ds_write_b64).
//   Phase 3: S=QK^T with triangular wave skip; maskless-fused softmax (no
//     max-subtract: logits bounded, fp32 exp safe).
//   Phase 4: P via per-wave scratch (C->A layout), PV from LDS V^T.

typedef __attribute__((ext_vector_type(8))) short short8;
typedef __attribute__((ext_vector_type(4))) float floatx4;

__device__ inline unsigned short f2bf(float f) {
  union { float f; unsigned u; } v; v.f = f;
  unsigned r = v.u + 0x7FFFu + ((v.u >> 16) & 1u);  // RNE
  return (unsigned short)(r >> 16);
}

__device__ inline void glds16(const void* g, void* l) {
  __builtin_amdgcn_global_load_lds(
      (const __attribute__((address_space(1))) void*)g,
      (__attribute__((address_space(3))) void*)l, 16, 0, 0);
}

// ---------------- kernel 0: weight transpose/convert (output-indexed) -------
__global__ void wt_kernel(const float* __restrict__ wq, const float* __restrict__ wk,
                          const float* __restrict__ wv, unsigned short* __restrict__ wt) {
  int idx = blockIdx.x * 256 + threadIdx.x;      // enumerates OUTPUT [mat][n][k]
  if (idx >= 3 * 64 * 384) return;
  int mat = idx / (64 * 384);
  int rem = idx % (64 * 384);
  int n = rem / 384, k = rem % 384;
  const float* w = (mat == 0) ? wq : ((mat == 1) ? wk : wv);
  wt[idx] = f2bf(w[k * 64 + n]);
}

// ---------------- kernel 1: fused QKV + attention ----------------
__global__ __launch_bounds__(1024) void fused_kernel(
    const float* __restrict__ x, const unsigned short* __restrict__ wt,
    float* __restrict__ out) {
  // wb[buf][kc][192 cols][32 k] bf16: 36864B per buffer. Reused as scratch later.
  __shared__ __align__(16) unsigned short wb[2][3 * 192 * 32];  // 73728 B
  __shared__ __align__(16) unsigned short sK[256 * 72];         // 36864 B
  __shared__ __align__(16) unsigned short sVT[64 * 264];        // 33792 B

  int tid = threadIdx.x, lane = tid & 63, w = tid >> 6;
  int m = lane & 15, q = lane >> 4;
  int b = blockIdx.x;
  const float* xb = x + (size_t)b * 256 * 384;

  // stage one mega-chunk (3 k-chunks of 32) of Wt into wb[buf]: 36 x 1KB issues
  auto stage = [&](int mega, int buf) {
#pragma unroll
    for (int t = 0; t < 3; ++t) {
      int i = w + 16 * t;
      if (i < 36) {
        int kc = i / 12, sub = i % 12;
        int c = sub * 16 + (lane >> 2), g = lane & 3;
        glds16(wt + (size_t)c * 384 + (mega * 3 + kc) * 32 + g * 8,
               (void*)&wb[buf][kc * 6144 + sub * 512]);
      }
    }
  };

  floatx4 z = {0.f, 0.f, 0.f, 0.f};
  floatx4 acc[12];
#pragma unroll
  for (int nt = 0; nt < 12; ++nt) acc[nt] = z;

  stage(0, 0);
#pragma unroll
  for (int mega = 0; mega < 4; ++mega) {
    int buf = mega & 1;
    __syncthreads();                    // wb[buf] staged; prior reads of buf^1 done
    if (mega < 3) stage(mega + 1, buf ^ 1);

#pragma unroll
    for (int kc = 0; kc < 3; ++kc) {
      int ks = mega * 3 + kc;
      // A: wave's 16 rows straight from global (16 x 128B segments, coalesced)
      const float* ap = xb + (size_t)(w * 16 + m) * 384 + ks * 32 + q * 8;
      float4 f0 = *(const float4*)ap;
      float4 f1 = *(const float4*)(ap + 4);
      short8 af;
      af[0] = (short)f2bf(f0.x); af[1] = (short)f2bf(f0.y);
      af[2] = (short)f2bf(f0.z); af[3] = (short)f2bf(f0.w);
      af[4] = (short)f2bf(f1.x); af[5] = (short)f2bf(f1.y);
      af[6] = (short)f2bf(f1.z); af[7] = (short)f2bf(f1.w);

      const unsigned short* wbk = &wb[buf][kc * 6144];
#pragma unroll
      for (int nt = 0; nt < 12; ++nt) {
        // granule = (4m+q) mod 8 -> uniform 8 lanes/group: conflict-free
        short8 bf = *(const short8*)&wbk[(nt * 16 + m) * 32 + q * 8];
        acc[nt] = __builtin_amdgcn_mfma_f32_16x16x32_bf16(af, bf, acc[nt], 0, 0, 0);
      }
    }
  }

  // ---------- epilogue: Q -> per-wave scratch (wb area), K -> sK, V^T -> sVT ----
  unsigned short* scr = &wb[0][0] + w * 1152;   // [16][72] bf16 per wave, 2304 B
#pragma unroll
  for (int nt = 0; nt < 8; ++nt) {
#pragma unroll
    for (int j = 0; j < 4; ++j) {
      unsigned short val = f2bf(acc[nt][j]);
      int lrow = q * 4 + j;                     // C-layout row within wave's 16
      if (nt < 4) scr[lrow * 72 + nt * 16 + m] = val;                  // Q
      else        sK[(w * 16 + lrow) * 72 + (nt - 4) * 16 + m] = val;  // K
    }
  }
#pragma unroll
  for (int nt = 8; nt < 12; ++nt) {             // V^T, packed 4 rows -> b64
    ushort4 pv;
    pv.x = f2bf(acc[nt][0]); pv.y = f2bf(acc[nt][1]);
    pv.z = f2bf(acc[nt][2]); pv.w = f2bf(acc[nt][3]);
    *(ushort4*)&sVT[((nt - 8) * 16 + m) * 264 + w * 16 + q * 4] = pv;
  }

  // Q fragments from own scratch (wave-local)
  short8 qf0 = *(const short8*)(scr + m * 72 + q * 8);
  short8 qf1 = *(const short8*)(scr + m * 72 + 32 + q * 8);

  __syncthreads();                              // sK, sVT visible to all waves

  // ---------- S = Q K^T (triangular: wave w needs col tiles nt <= w) ----------
  floatx4 sacc[16];
#pragma unroll
  for (int nt = 0; nt < 16; ++nt) {
    if (nt > w) continue;                       // wave-uniform skip
    short8 kb0 = *(const short8*)(sK + (nt * 16 + m) * 72 + q * 8);
    short8 kb1 = *(const short8*)(sK + (nt * 16 + m) * 72 + 32 + q * 8);
    floatx4 t = __builtin_amdgcn_mfma_f32_16x16x32_bf16(qf0, kb0, z, 0, 0, 0);
    sacc[nt] = __builtin_amdgcn_mfma_f32_16x16x32_bf16(qf1, kb1, t, 0, 0, 0);
  }

  // ---------- fused causal mask + softmax (no max-subtract) ----------
  const float CSC = 0.18033688011112042f;       // log2(e)/sqrt(64)
  float inv_[4];
  int rbase = w * 16 + q * 4;
#pragma unroll
  for (int j = 0; j < 4; ++j) {
    int rg = rbase + j;
    float sum = 0.f;
#pragma unroll
    for (int nt = 0; nt < 16; ++nt) {
      if (nt > w) continue;
      int col = nt * 16 + m;
      float p = (col <= rg) ? exp2f(sacc[nt][j] * CSC) : 0.f;
      sacc[nt][j] = p;
      sum += p;
    }
    sum += __shfl_xor(sum, 1);
    sum += __shfl_xor(sum, 2);
    sum += __shfl_xor(sum, 4);
    sum += __shfl_xor(sum, 8);
    inv_[j] = 1.f / sum;                        // diagonal term -> sum >= 1
  }

  // ---------- O = P V, chunked by 64 k-cols through per-wave scratch ----------
  floatx4 o[4];
#pragma unroll
  for (int vt = 0; vt < 4; ++vt) o[vt] = z;
#pragma unroll
  for (int c = 0; c < 4; ++c) {
    if (4 * c > w) continue;                    // chunk needed iff 64c <= 16w+15
#pragma unroll
    for (int t = 0; t < 4; ++t) {
      int nt = 4 * c + t;
#pragma unroll
      for (int j = 0; j < 4; ++j) {
        unsigned short pv = (nt <= w) ? f2bf(sacc[nt][j] * inv_[j]) : (unsigned short)0;
        scr[(q * 4 + j) * 72 + t * 16 + m] = pv;
      }
    }
    short8 pf0 = *(const short8*)(scr + m * 72 + q * 8);
    short8 pf1 = *(const short8*)(scr + m * 72 + 32 + q * 8);
#pragma unroll
    for (int vt = 0; vt < 4; ++vt) {
      short8 vb0 = *(const short8*)(sVT + (vt * 16 + m) * 264 + c * 64 + q * 8);
      short8 vb1 = *(const short8*)(sVT + (vt * 16 + m) * 264 + c * 64 + 32 + q * 8);
      o[vt] = __builtin_amdgcn_mfma_f32_16x16x32_bf16(pf0, vb0, o[vt], 0, 0, 0);
      o[vt] = __builtin_amdgcn_mfma_f32_16x16x32_bf16(pf1, vb1, o[vt], 0, 0, 0);
    }
  }

  // ---------- store O ----------
  float* op = out + ((size_t)b * 256 + w * 16) * 64;
#pragma unroll
  for (int vt = 0; vt < 4; ++vt)
#pragma unroll
    for (int j = 0; j < 4; ++j)
      op[(q * 4 + j) * 64 + vt * 16 + m] = o[vt][j];
}

extern "C" void kernel_launch(void* const* d_in, const int* in_sizes, int n_in,
                              void* d_out, int out_size, void* d_ws, size_t ws_size,
                              hipStream_t stream) {
  const float* x  = (const float*)d_in[0];
  const float* wq = (const float*)d_in[1];
  const float* wk = (const float*)d_in[2];
  const float* wv = (const float*)d_in[3];
  float* out = (float*)d_out;

  unsigned short* wt = (unsigned short*)d_ws;   // Wt bf16 [192][384] = 147456 B

  wt_kernel<<<288, 256, 0, stream>>>(wq, wk, wv, wt);
  fused_kernel<<<256, 1024, 0, stream>>>(x, wt, out);
}